// Round 8
// baseline (373.191 us; speedup 1.0000x reference)
//
#include <hip/hip_runtime.h>

// Fused 2-layer GRU, round 8: autonomous layer-waves, barrier every 8 steps.
// S=256, B=8192, IN=1, H=32, L=2.
//
// 512 blocks x 128 thr (2 waves); block owns 16 batch elements.
// Wave 0: ALL of layer 0 (6 MFMA tiles/step). Wave 1: ALL of layer 1
// (12 MFMA tiles/step), lagged one 8-step segment.
// Each layer's recurrence is wave-private: the D-layout -> B-fragment
// transpose is an intra-wave LDS write->read (compiler lgkm-ordered, no
// barrier). Wave 0 publishes h0 into a 16-slot ring (B-frag layout, bf16);
// wave 1 reads the PREVIOUS segment's slots, so B0(t+1) is prefetched a
// full step early (ring entry already exists). __syncthreads only at
// segment boundaries (33 total vs 257 in R6). No global ops in the loop.

#define S_LEN 256
#define B_SZ  8192
#define H_SZ  32
#define RS    40      // LDS row stride in shorts (80 B)
#define SEG   8
#define NSLOT 16      // 2*SEG ring slots

typedef __attribute__((ext_vector_type(8))) short short8;  // 8 bf16
typedef __attribute__((ext_vector_type(4))) float f32x4;   // MFMA C/D

#define MFMA(a, b, c) __builtin_amdgcn_mfma_f32_16x16x32_bf16(a, b, c, 0, 0, 0)

#if __has_builtin(__builtin_amdgcn_exp2f)
#define EXP2F(x) __builtin_amdgcn_exp2f(x)
#else
#define EXP2F(x) exp2f(x)
#endif
#if __has_builtin(__builtin_amdgcn_rcpf)
#define RCPF(x) __builtin_amdgcn_rcpf(x)
#else
#define RCPF(x) (1.0f / (x))
#endif

__device__ __forceinline__ float sigm_pre(float p) {   // p = -log2e * v
    return RCPF(1.0f + EXP2F(p));
}
__device__ __forceinline__ float tanh_pre(float p) {   // p = 2*log2e * v
    return 1.0f - 2.0f * RCPF(1.0f + EXP2F(p));
}

__device__ __forceinline__ unsigned short bf_rne1(float f) {
    union { float f; unsigned u; } x; x.f = f;
    unsigned u = x.u + 0x7fffu + ((x.u >> 16) & 1u);
    return (unsigned short)(u >> 16);
}

#if __has_builtin(__builtin_amdgcn_cvt_pk_bf16_f32)
typedef __bf16 bf16x2 __attribute__((ext_vector_type(2)));
__device__ __forceinline__ unsigned pk2(float a, float b) {
    union { bf16x2 v; unsigned u; } c;
    c.v = __builtin_amdgcn_cvt_pk_bf16_f32(a, b);
    return c.u;
}
#else
__device__ __forceinline__ unsigned pk2(float a, float b) {
    return (unsigned)bf_rne1(a) | ((unsigned)bf_rne1(b) << 16);
}
#endif

__global__ __launch_bounds__(128, 1) void gru_auto(
    const float* __restrict__ x,      // (S,B,1)
    const float* __restrict__ h_in,   // (2,B,H)
    const float* __restrict__ W_ih0,  // (96,1)
    const float* __restrict__ W_hh0,  // (96,32)
    const float* __restrict__ b_ih0,  // (96)
    const float* __restrict__ b_hh0,  // (96)
    const float* __restrict__ W_ih1,  // (96,32)
    const float* __restrict__ W_hh1,  // (96,32)
    const float* __restrict__ b_ih1,  // (96)
    const float* __restrict__ b_hh1,  // (96)
    const float* __restrict__ W_out,  // (1,32)
    const float* __restrict__ b_out,  // (1)
    float* __restrict__ out)          // y (S*B) then h_state (2,B,H)
{
    __shared__ __align__(16) unsigned short ring[NSLOT][16 * RS]; // 20.5 KB
    __shared__ __align__(16) unsigned short tr1[16 * RS];         // 1.3 KB
    __shared__ __align__(16) float sx[S_LEN * 16];                // 16 KB
    __shared__ __align__(16) float sy[S_LEN * 16];                // 16 KB

    const int tid  = threadIdx.x;
    const int w    = tid >> 6;        // 0 -> layer 0, 1 -> layer 1
    const int lane = tid & 63;
    const int n    = lane & 15;       // batch col / A-row index
    const int q    = lane >> 4;       // quad
    const int base = blockIdx.x * 16;
    const int bn   = base + n;

    // ---- stage x (coalesced float4, both waves) ----
    for (int s = tid; s < S_LEN * 4; s += 128) {
        const int t = s >> 2, c = s & 3;
        *(float4*)&sx[t * 16 + c * 4] = *(const float4*)&x[t * B_SZ + base + c * 4];
    }

    const float SRZ = -1.4426950408889634f;  // -log2(e)   (sigmoid gates)
    const float SN  =  2.8853900817779268f;  //  2*log2(e) (tanh gate)

    // ---- persistent per-role state ----
    // Tiles T=0..5: gate = T>>1 (r,z,n), hidden half hidx = T&1.
    short8 Am[6], Aa[6];              // main (hh / L0) and aux (L1 ih) A-frags
    f32x4  Cm[6], Ca[2];              // folded-bias C operands
    float  wir[2][4], wiz[2][4], win[2][4], bin[2][4];  // w0 x-weights
    float  wo[2][4];                                     // w1 head weights
    float  hd[2][4];                                     // own h, fp32 D-layout
    short8 B0, B1, B0n;

    if (w == 0) {
#pragma unroll
        for (int T = 0; T < 6; ++T) {
            const float sc = (T < 4) ? SRZ : SN;
            const int row = 16 * T + n;
#pragma unroll
            for (int e = 0; e < 8; ++e)
                Am[T][e] = (short)bf_rne1(W_hh0[row * H_SZ + q * 8 + e] * sc);
#pragma unroll
            for (int r = 0; r < 4; ++r) {
                const int g = 16 * T + 4 * q + r;
                Cm[T][r] = (T < 4) ? SRZ * (b_ih0[g] + b_hh0[g])
                                   : SN * b_hh0[g];
            }
        }
#pragma unroll
        for (int h = 0; h < 2; ++h)
#pragma unroll
            for (int r = 0; r < 4; ++r) {
                const int j = 16 * h + 4 * q + r;
                wir[h][r] = SRZ * W_ih0[j];
                wiz[h][r] = SRZ * W_ih0[32 + j];
                win[h][r] = SN  * W_ih0[64 + j];
                bin[h][r] = SN  * b_ih0[64 + j];
                hd[h][r]  = h_in[bn * H_SZ + j];
            }
        // initial B0 = h0(-1) bf16
        union { short8 s8; unsigned u[4]; } f;
        const float4 a = *(const float4*)&h_in[bn * H_SZ + q * 8];
        const float4 b = *(const float4*)&h_in[bn * H_SZ + q * 8 + 4];
        f.u[0] = pk2(a.x, a.y); f.u[1] = pk2(a.z, a.w);
        f.u[2] = pk2(b.x, b.y); f.u[3] = pk2(b.z, b.w);
        B0 = f.s8;
    } else {
#pragma unroll
        for (int T = 0; T < 6; ++T) {
            const float sc = (T < 4) ? SRZ : SN;
            const int row = 16 * T + n;
#pragma unroll
            for (int e = 0; e < 8; ++e) {
                Am[T][e] = (short)bf_rne1(W_hh1[row * H_SZ + q * 8 + e] * sc);
                Aa[T][e] = (short)bf_rne1(W_ih1[row * H_SZ + q * 8 + e] * sc);
            }
#pragma unroll
            for (int r = 0; r < 4; ++r) {
                const int g = 16 * T + 4 * q + r;
                Cm[T][r] = (T < 4) ? SRZ * (b_ih1[g] + b_hh1[g])
                                   : SN * b_hh1[g];
                if (T >= 4) Ca[T - 4][r] = SN * b_ih1[g];
            }
        }
#pragma unroll
        for (int h = 0; h < 2; ++h)
#pragma unroll
            for (int r = 0; r < 4; ++r) {
                const int j = 16 * h + 4 * q + r;
                hd[h][r] = h_in[B_SZ * H_SZ + bn * H_SZ + j];
                wo[h][r] = W_out[j];
            }
        // initial B1 = h1(-1) bf16
        union { short8 s8; unsigned u[4]; } f;
        const float4 a = *(const float4*)&h_in[B_SZ * H_SZ + bn * H_SZ + q * 8];
        const float4 b = *(const float4*)&h_in[B_SZ * H_SZ + bn * H_SZ + q * 8 + 4];
        f.u[0] = pk2(a.x, a.y); f.u[1] = pk2(a.z, a.w);
        f.u[2] = pk2(b.x, b.y); f.u[3] = pk2(b.z, b.w);
        B1 = f.s8;
    }
    const f32x4 Z4 = {0.f, 0.f, 0.f, 0.f};
    const float bout = b_out[0];

    const int lsr  = n * RS + 8 * q;        // b128 read offset (shorts)
    const int lsw0 = n * RS + 4 * q;        // b64 write, hidden 0..15
    const int lsw1 = n * RS + 16 + 4 * q;   // b64 write, hidden 16..31

    __syncthreads();   // x staged

#pragma unroll 1
    for (int m = 0; m <= S_LEN / SEG; ++m) {
        if (w == 0) {
            if (m < S_LEN / SEG) {
#pragma unroll 1
                for (int k = 0; k < SEG; ++k) {
                    const int t = m * SEG + k;
                    f32x4 D[6];
#pragma unroll
                    for (int T = 0; T < 6; ++T) D[T] = MFMA(Am[T], B0, Cm[T]);
                    const float xc = sx[t * 16 + n];
                    unsigned short* slot = &ring[t & (NSLOT - 1)][0];
                    float hv[2][4];
#pragma unroll
                    for (int h = 0; h < 2; ++h)
#pragma unroll
                        for (int r = 0; r < 4; ++r) {
                            const float rg = sigm_pre(fmaf(xc, wir[h][r], D[h][r]));
                            const float zg = sigm_pre(fmaf(xc, wiz[h][r], D[2 + h][r]));
                            const float ng = tanh_pre(fmaf(rg, D[4 + h][r],
                                                           fmaf(xc, win[h][r], bin[h][r])));
                            const float v = fmaf(zg, hd[h][r] - ng, ng);
                            hd[h][r] = v;
                            hv[h][r] = v;
                        }
                    *(uint2*)&slot[lsw0] =
                        make_uint2(pk2(hv[0][0], hv[0][1]), pk2(hv[0][2], hv[0][3]));
                    *(uint2*)&slot[lsw1] =
                        make_uint2(pk2(hv[1][0], hv[1][1]), pk2(hv[1][2], hv[1][3]));
                    B0 = *(const short8*)&slot[lsr];   // own B0 for step t+1
                }
            }
        } else {
            if (m > 0) {
                const int t0 = (m - 1) * SEG;
                B0 = *(const short8*)&ring[t0 & (NSLOT - 1)][lsr];
#pragma unroll 1
                for (int k = 0; k < SEG; ++k) {
                    const int t = t0 + k;
                    f32x4 U[6], V[6];
#pragma unroll
                    for (int T = 0; T < 6; ++T) U[T] = MFMA(Am[T], B1, Cm[T]);
#pragma unroll
                    for (int T = 0; T < 6; ++T)
                        V[T] = MFMA(Aa[T], B0, (T >= 4) ? Ca[T - 4] : Z4);
                    if (k + 1 < SEG)   // prefetch next B0 (same synced half)
                        B0n = *(const short8*)&ring[(t + 1) & (NSLOT - 1)][lsr];
                    float hv[2][4];
                    float ys = 0.f;
#pragma unroll
                    for (int h = 0; h < 2; ++h)
#pragma unroll
                        for (int r = 0; r < 4; ++r) {
                            const float rg = sigm_pre(U[h][r] + V[h][r]);
                            const float zg = sigm_pre(U[2 + h][r] + V[2 + h][r]);
                            const float ng = tanh_pre(fmaf(rg, U[4 + h][r], V[4 + h][r]));
                            const float v = fmaf(zg, hd[h][r] - ng, ng);
                            hd[h][r] = v;
                            hv[h][r] = v;
                            ys = fmaf(v, wo[h][r], ys);
                        }
                    *(uint2*)&tr1[lsw0] =
                        make_uint2(pk2(hv[0][0], hv[0][1]), pk2(hv[0][2], hv[0][3]));
                    *(uint2*)&tr1[lsw1] =
                        make_uint2(pk2(hv[1][0], hv[1][1]), pk2(hv[1][2], hv[1][3]));
                    B1 = *(const short8*)&tr1[lsr];    // own B1 for step t+1
                    ys += __shfl_xor(ys, 16);
                    ys += __shfl_xor(ys, 32);
                    if (lane < 16) sy[t * 16 + n] = ys;
                    B0 = B0n;
                }
            }
        }
        __syncthreads();   // segment boundary: publish ring half / sy
    }

    // ---- flush y (coalesced float4 + bias) ----
    for (int s = tid; s < S_LEN * 4; s += 128) {
        const int t = s >> 2, c = s & 3;
        const float4 a = *(const float4*)&sy[t * 16 + c * 4];
        *(float4*)&out[t * B_SZ + base + c * 4] =
            make_float4(a.x + bout, a.y + bout, a.z + bout, a.w + bout);
    }

    // ---- final h_state: out = y (S*B) ++ h0 (B*H) ++ h1 (B*H) ----
    const size_t hoff = (size_t)S_LEN * B_SZ + (size_t)(w == 1) * B_SZ * H_SZ;
#pragma unroll
    for (int h = 0; h < 2; ++h)
        *(float4*)&out[hoff + bn * H_SZ + 16 * h + 4 * q] =
            make_float4(hd[h][0], hd[h][1], hd[h][2], hd[h][3]);
}

extern "C" void kernel_launch(void* const* d_in, const int* in_sizes, int n_in,
                              void* d_out, int out_size, void* d_ws, size_t ws_size,
                              hipStream_t stream) {
    (void)in_sizes; (void)n_in; (void)out_size; (void)d_ws; (void)ws_size;
    const float* x     = (const float*)d_in[0];
    const float* h_in  = (const float*)d_in[1];
    const float* W_ih0 = (const float*)d_in[2];
    const float* W_hh0 = (const float*)d_in[3];
    const float* b_ih0 = (const float*)d_in[4];
    const float* b_hh0 = (const float*)d_in[5];
    const float* W_ih1 = (const float*)d_in[6];
    const float* W_hh1 = (const float*)d_in[7];
    const float* b_ih1 = (const float*)d_in[8];
    const float* b_hh1 = (const float*)d_in[9];
    const float* W_out = (const float*)d_in[10];
    const float* b_out = (const float*)d_in[11];

    dim3 grid(B_SZ / 16);   // 512 blocks x 2 waves = 1024 waves
    dim3 block(128);
    gru_auto<<<grid, block, 0, stream>>>(x, h_in, W_ih0, W_hh0, b_ih0, b_hh0,
                                         W_ih1, W_hh1, b_ih1, b_hh1,
                                         W_out, b_out, (float*)d_out);
}

// Round 9
// 317.548 us; speedup vs baseline: 1.1752x; 1.1752x over previous
//
#include <hip/hip_runtime.h>

// Fused 2-layer GRU, round 9: R6 exchange scheme + r-split waves (redundant
// MFMA) + lag-prefetch for L1. S=256, B=8192, IN=1, H=32, L=2.
//
// 512 blocks x 512 thr (8 waves); block owns 16 batch elements.
// Wave id w: layer = w>>2 (0/1), hl = (w>>1)&1 (hidden half), rp = w&1
// (accumulator-register pair r in {2rp, 2rp+1}).
// Each wave computes its layer+half's 3 gate tiles as FULL MFMAs (redundant
// across the rp pair -- MFMA pipe is ~6% busy, trans/VALU issue is the
// bottleneck) but epilogues only its 2 register rows: per-wave trans issue
// halves vs R6 and wave count doubles to 4096 (4/SIMD).
// L1 waves run one step behind (step i-1 at iter i): their B0/B1 fragments
// are read one barrier BEFORE use -> zero read->MFMA stall. L0 keeps the
// tight loop (true recurrence dependency). Triple-buffered bf16 h exchange
// (B-fragment layout, direct ds_read_b128). No global ops inside the loop.
// y computed by wave 4 from its own just-read B1 fragment (bf16 source,
// R7-validated numerics).

#define S_LEN 256
#define B_SZ  8192
#define H_SZ  32
#define RS    40     // LDS row stride in shorts (80 B)

typedef __attribute__((ext_vector_type(8))) short short8;  // 8 bf16
typedef __attribute__((ext_vector_type(4))) float f32x4;   // MFMA C/D

#define MFMA(a, b, c) __builtin_amdgcn_mfma_f32_16x16x32_bf16(a, b, c, 0, 0, 0)

#if __has_builtin(__builtin_amdgcn_exp2f)
#define EXP2F(x) __builtin_amdgcn_exp2f(x)
#else
#define EXP2F(x) exp2f(x)
#endif
#if __has_builtin(__builtin_amdgcn_rcpf)
#define RCPF(x) __builtin_amdgcn_rcpf(x)
#else
#define RCPF(x) (1.0f / (x))
#endif

__device__ __forceinline__ float sigm_pre(float p) {   // p = -log2e * v
    return RCPF(1.0f + EXP2F(p));
}
__device__ __forceinline__ float tanh_pre(float p) {   // p = 2*log2e * v
    return 1.0f - 2.0f * RCPF(1.0f + EXP2F(p));
}

__device__ __forceinline__ unsigned short bf_rne1(float f) {
    union { float f; unsigned u; } x; x.f = f;
    unsigned u = x.u + 0x7fffu + ((x.u >> 16) & 1u);
    return (unsigned short)(u >> 16);
}

#if __has_builtin(__builtin_amdgcn_cvt_pk_bf16_f32)
typedef __bf16 bf16x2 __attribute__((ext_vector_type(2)));
__device__ __forceinline__ unsigned pk2(float a, float b) {
    union { bf16x2 v; unsigned u; } c;
    c.v = __builtin_amdgcn_cvt_pk_bf16_f32(a, b);
    return c.u;
}
#else
__device__ __forceinline__ unsigned pk2(float a, float b) {
    return (unsigned)bf_rne1(a) | ((unsigned)bf_rne1(b) << 16);
}
#endif

__device__ __forceinline__ float bits_f(unsigned u) {
    union { unsigned u; float f; } x; x.u = u; return x.f;
}

__global__ __launch_bounds__(512, 4) void gru_rsplit(
    const float* __restrict__ x,      // (S,B,1)
    const float* __restrict__ h_in,   // (2,B,H)
    const float* __restrict__ W_ih0,  // (96,1)
    const float* __restrict__ W_hh0,  // (96,32)
    const float* __restrict__ b_ih0,  // (96)
    const float* __restrict__ b_hh0,  // (96)
    const float* __restrict__ W_ih1,  // (96,32)
    const float* __restrict__ W_hh1,  // (96,32)
    const float* __restrict__ b_ih1,  // (96)
    const float* __restrict__ b_hh1,  // (96)
    const float* __restrict__ W_out,  // (1,32)
    const float* __restrict__ b_out,  // (1)
    float* __restrict__ out)          // y (S*B) then h_state (2,B,H)
{
    __shared__ __align__(16) unsigned short sh0[3][16 * RS];  // h0 bf16
    __shared__ __align__(16) unsigned short sh1[3][16 * RS];  // h1 bf16
    __shared__ __align__(16) float sx[S_LEN * 16];            // staged x
    __shared__ __align__(16) float sy[S_LEN * 16];            // buffered y

    const int tid   = threadIdx.x;
    const int w     = tid >> 6;        // 0..7
    const int lane  = tid & 63;
    const int n     = lane & 15;       // batch col / A-row index
    const int q     = lane >> 4;       // quad
    const int layer = w >> 2;          // 0: L0 waves, 1: L1 waves
    const int hl    = (w >> 1) & 1;    // hidden half (gate rows 16*hl..+16)
    const int rp    = w & 1;           // register pair: r in {2rp, 2rp+1}
    const int base  = blockIdx.x * 16;
    const int bn    = base + n;

    // ---- stage x (coalesced float4, all waves) ----
    for (int s = tid; s < S_LEN * 4; s += 512) {
        const int t = s >> 2, c = s & 3;
        *(float4*)&sx[t * 16 + c * 4] = *(const float4*)&x[t * B_SZ + base + c * 4];
    }

    const float SRZ = -1.4426950408889634f;  // -log2(e)   (sigmoid gates)
    const float SN  =  2.8853900817779268f;  //  2*log2(e) (tanh gate)

    // ---- persistent weights for this wave's (layer, hl) tiles ----
    const float* Wm = layer ? W_hh1 : W_hh0;   // recurrent matrix
    const float* bi = layer ? b_ih1 : b_ih0;
    const float* bh = layer ? b_hh1 : b_hh0;

    short8 Ar, Az, An, Pr, Pz, Pn;   // A-frags: recurrent; L1 ih-side
    f32x4  Cr, Cz, Cn, Ci;           // folded-bias C operands
    {
        const int rowr = 16 * hl + n;        // r-gate tile row (m = n)
        const int rowz = 32 + 16 * hl + n;
        const int rown = 64 + 16 * hl + n;
#pragma unroll
        for (int e = 0; e < 8; ++e) {
            Ar[e] = (short)bf_rne1(Wm[rowr * H_SZ + q * 8 + e] * SRZ);
            Az[e] = (short)bf_rne1(Wm[rowz * H_SZ + q * 8 + e] * SRZ);
            An[e] = (short)bf_rne1(Wm[rown * H_SZ + q * 8 + e] * SN);
        }
        if (layer) {
#pragma unroll
            for (int e = 0; e < 8; ++e) {
                Pr[e] = (short)bf_rne1(W_ih1[rowr * H_SZ + q * 8 + e] * SRZ);
                Pz[e] = (short)bf_rne1(W_ih1[rowz * H_SZ + q * 8 + e] * SRZ);
                Pn[e] = (short)bf_rne1(W_ih1[rown * H_SZ + q * 8 + e] * SN);
            }
        }
#pragma unroll
        for (int r = 0; r < 4; ++r) {
            const int g = 16 * hl + 4 * q + r;     // row within the gate
            Cr[r] = SRZ * (bi[g] + bh[g]);
            Cz[r] = SRZ * (bi[32 + g] + bh[32 + g]);
            Cn[r] = SN * bh[64 + g];               // n-gate: b_hh on gh side
            Ci[r] = SN * bi[64 + g];
        }
    }
    // L0 input weights for this wave's two rows j = 16hl+4q+2rp+s
    float wir[2], wiz[2], win[2], bin[2];
    if (!layer) {
#pragma unroll
        for (int s = 0; s < 2; ++s) {
            const int j = 16 * hl + 4 * q + 2 * rp + s;
            wir[s] = SRZ * W_ih0[j];
            wiz[s] = SRZ * W_ih0[32 + j];
            win[s] = SN  * W_ih0[64 + j];
            bin[s] = SN  * b_ih0[64 + j];
        }
    }
    float wo8[8];
    if (w == 4) {
#pragma unroll
        for (int e = 0; e < 8; ++e) wo8[e] = W_out[q * 8 + e];
    }
    const f32x4 Z4 = {0.f, 0.f, 0.f, 0.f};
    const float bout = b_out[0];

    // ---- own h slice (2 fp32) + initial B fragment ----
    float hd[2];
    {
        const float* hsrc = h_in + (size_t)layer * B_SZ * H_SZ + bn * H_SZ;
        hd[0] = hsrc[16 * hl + 4 * q + 2 * rp];
        hd[1] = hsrc[16 * hl + 4 * q + 2 * rp + 1];
    }
    short8 B0, B1;
    {
        const float* hsrc = h_in + (size_t)layer * B_SZ * H_SZ + bn * H_SZ + q * 8;
        union { short8 s8; unsigned u[4]; } f;
        const float4 a = *(const float4*)&hsrc[0];
        const float4 b = *(const float4*)&hsrc[4];
        f.u[0] = pk2(a.x, a.y); f.u[1] = pk2(a.z, a.w);
        f.u[2] = pk2(b.x, b.y); f.u[3] = pk2(b.z, b.w);
        if (layer) B1 = f.s8; else B0 = f.s8;
    }

    const int wroff = n * RS + 16 * hl + 4 * q + 2 * rp;  // b32 write (shorts)
    const int rdoff = n * RS + 8 * q;                     // b128 read (shorts)

    __syncthreads();   // x staged

    int bw = 0;        // rotating buffer index (i % 3)
#pragma unroll 1
    for (int i = 0; i <= S_LEN; ++i) {
        // ---------------- pre-barrier compute ----------------
        if (layer == 0) {
            if (i < S_LEN) {
                // h0(i) from B0 = h0(i-1) (read last iter, ~true-dep stall)
                const f32x4 Dr = MFMA(Ar, B0, Cr);
                const f32x4 Dz = MFMA(Az, B0, Cz);
                const f32x4 Dn = MFMA(An, B0, Cn);
                const float xc = sx[i * 16 + n];
                float hv0, hv1;
#pragma unroll
                for (int s = 0; s < 2; ++s) {
                    const int rr = 2 * rp + s;
                    const float rg = sigm_pre(fmaf(xc, wir[s], Dr[rr]));
                    const float zg = sigm_pre(fmaf(xc, wiz[s], Dz[rr]));
                    const float ng = tanh_pre(fmaf(rg, Dn[rr],
                                                   fmaf(xc, win[s], bin[s])));
                    const float v = fmaf(zg, hd[s] - ng, ng);
                    hd[s] = v;
                    if (s == 0) hv0 = v; else hv1 = v;
                }
                *(unsigned*)&sh0[bw][wroff] = pk2(hv0, hv1);
            }
        } else {
            if (i > 0) {
                // h1(i-1) from B1 = h1(i-2), B0 = h0(i-1): both prefetched
                // one full barrier ago -> zero read stall here.
                const f32x4 Ur = MFMA(Ar, B1, Cr);
                const f32x4 Uz = MFMA(Az, B1, Cz);
                const f32x4 Un = MFMA(An, B1, Cn);
                const f32x4 Vr = MFMA(Pr, B0, Z4);
                const f32x4 Vz = MFMA(Pz, B0, Z4);
                const f32x4 Vn = MFMA(Pn, B0, Ci);
                float hv0, hv1;
#pragma unroll
                for (int s = 0; s < 2; ++s) {
                    const int rr = 2 * rp + s;
                    const float rg = sigm_pre(Ur[rr] + Vr[rr]);
                    const float zg = sigm_pre(Uz[rr] + Vz[rr]);
                    const float ng = tanh_pre(fmaf(rg, Un[rr], Vn[rr]));
                    const float v = fmaf(zg, hd[s] - ng, ng);
                    hd[s] = v;
                    if (s == 0) hv0 = v; else hv1 = v;
                }
                *(unsigned*)&sh1[bw][wroff] = pk2(hv0, hv1);
            }
        }

        __syncthreads();   // lgkm-only drain (no global ops in loop)

        // ---------------- post-barrier prefetch reads ----------------
        if (layer == 0) {
            if (i < S_LEN)
                B0 = *(const short8*)&sh0[bw][rdoff];   // h0(i), used iter i+1
        } else {
            if (i < S_LEN)
                B0 = *(const short8*)&sh0[bw][rdoff];   // h0(i) for step i
            if (i > 0) {
                B1 = *(const short8*)&sh1[bw][rdoff];   // h1(i-1) for step i
                if (w == 4) {
                    // y(i-1) from the B1 fragment just read (bf16 source)
                    union { short8 s8; unsigned u[4]; } f; f.s8 = B1;
                    float ys = bits_f(f.u[0] << 16) * wo8[0];
                    ys = fmaf(bits_f(f.u[0] & 0xffff0000u), wo8[1], ys);
                    ys = fmaf(bits_f(f.u[1] << 16),         wo8[2], ys);
                    ys = fmaf(bits_f(f.u[1] & 0xffff0000u), wo8[3], ys);
                    ys = fmaf(bits_f(f.u[2] << 16),         wo8[4], ys);
                    ys = fmaf(bits_f(f.u[2] & 0xffff0000u), wo8[5], ys);
                    ys = fmaf(bits_f(f.u[3] << 16),         wo8[6], ys);
                    ys = fmaf(bits_f(f.u[3] & 0xffff0000u), wo8[7], ys);
                    ys += __shfl_xor(ys, 16);
                    ys += __shfl_xor(ys, 32);
                    if (lane < 16) sy[(i - 1) * 16 + n] = ys;
                }
            }
        }
        bw = (bw == 2) ? 0 : bw + 1;
    }

    __syncthreads();   // sy complete

    // ---- flush y (coalesced float4 + bias) ----
    for (int s = tid; s < S_LEN * 4; s += 512) {
        const int t = s >> 2, c = s & 3;
        const float4 a = *(const float4*)&sy[t * 16 + c * 4];
        *(float4*)&out[t * B_SZ + base + c * 4] =
            make_float4(a.x + bout, a.y + bout, a.z + bout, a.w + bout);
    }

    // ---- final h_state: out = y (S*B) ++ h0 (B*H) ++ h1 (B*H) ----
    const size_t hoff = (size_t)S_LEN * B_SZ + (size_t)layer * B_SZ * H_SZ;
    *(float2*)&out[hoff + bn * H_SZ + 16 * hl + 4 * q + 2 * rp] =
        make_float2(hd[0], hd[1]);
}

extern "C" void kernel_launch(void* const* d_in, const int* in_sizes, int n_in,
                              void* d_out, int out_size, void* d_ws, size_t ws_size,
                              hipStream_t stream) {
    (void)in_sizes; (void)n_in; (void)out_size; (void)d_ws; (void)ws_size;
    const float* x     = (const float*)d_in[0];
    const float* h_in  = (const float*)d_in[1];
    const float* W_ih0 = (const float*)d_in[2];
    const float* W_hh0 = (const float*)d_in[3];
    const float* b_ih0 = (const float*)d_in[4];
    const float* b_hh0 = (const float*)d_in[5];
    const float* W_ih1 = (const float*)d_in[6];
    const float* W_hh1 = (const float*)d_in[7];
    const float* b_ih1 = (const float*)d_in[8];
    const float* b_hh1 = (const float*)d_in[9];
    const float* W_out = (const float*)d_in[10];
    const float* b_out = (const float*)d_in[11];

    dim3 grid(B_SZ / 16);   // 512 blocks x 8 waves = 4096 waves (4/SIMD)
    dim3 block(512);
    gru_rsplit<<<grid, block, 0, stream>>>(x, h_in, W_ih0, W_hh0, b_ih0, b_hh0,
                                           W_ih1, W_hh1, b_ih1, b_hh1,
                                           W_out, b_out, (float*)d_out);
}

// Round 10
// 267.319 us; speedup vs baseline: 1.3961x; 1.1879x over previous
//
#include <hip/hip_runtime.h>

// Fused 2-layer GRU, round 10: R6 geometry + L1 lag-prefetch + short L0 path.
// S=256, B=8192, IN=1, H=32, L=2.
//
// 512 blocks x 256 thr (4 waves); block owns 16 batch elements.
// Waves 0,1: layer 0 (hidden half wl=w&1) -- the TRUE-dependency path:
//   barrier -> read B0=h0(i-1) -> 3 MFMA -> epilogue -> write h0(i).
// Waves 2,3: layer 1, lagged ONE step: at iter i they compute h1(i-1) from
//   B0=h0(i-1), B1=h1(i-2), both read at iter i-1 post-barrier -> ZERO
//   post-barrier dependency (R9-validated pattern). Wave 2 computes y(i-1)
//   from its just-read B1 fragment (bf16 source, R7-validated numerics).
// One barrier per iter; 2 LDS buffers (buf=i&1; barrier bounds skew <1 iter).
// h exchanged in bf16 B-fragment layout (direct ds_read_b128, zero repack).
// No global ops inside the loop (x staged to LDS, y buffered in LDS).

#define S_LEN 256
#define B_SZ  8192
#define H_SZ  32
#define RS    40     // LDS row stride in shorts (80 B)

typedef __attribute__((ext_vector_type(8))) short short8;  // 8 bf16
typedef __attribute__((ext_vector_type(4))) float f32x4;   // MFMA C/D

#define MFMA(a, b, c) __builtin_amdgcn_mfma_f32_16x16x32_bf16(a, b, c, 0, 0, 0)

#if __has_builtin(__builtin_amdgcn_exp2f)
#define EXP2F(x) __builtin_amdgcn_exp2f(x)
#else
#define EXP2F(x) exp2f(x)
#endif
#if __has_builtin(__builtin_amdgcn_rcpf)
#define RCPF(x) __builtin_amdgcn_rcpf(x)
#else
#define RCPF(x) (1.0f / (x))
#endif

__device__ __forceinline__ float sigm_pre(float p) {   // p = -log2e * v
    return RCPF(1.0f + EXP2F(p));
}
__device__ __forceinline__ float tanh_pre(float p) {   // p = 2*log2e * v
    return 1.0f - 2.0f * RCPF(1.0f + EXP2F(p));
}

__device__ __forceinline__ unsigned short bf_rne1(float f) {
    union { float f; unsigned u; } x; x.f = f;
    unsigned u = x.u + 0x7fffu + ((x.u >> 16) & 1u);
    return (unsigned short)(u >> 16);
}

#if __has_builtin(__builtin_amdgcn_cvt_pk_bf16_f32)
typedef __bf16 bf16x2 __attribute__((ext_vector_type(2)));
__device__ __forceinline__ unsigned pk2(float a, float b) {
    union { bf16x2 v; unsigned u; } c;
    c.v = __builtin_amdgcn_cvt_pk_bf16_f32(a, b);
    return c.u;
}
#else
__device__ __forceinline__ unsigned pk2(float a, float b) {
    return (unsigned)bf_rne1(a) | ((unsigned)bf_rne1(b) << 16);
}
#endif

__device__ __forceinline__ float bits_f(unsigned u) {
    union { unsigned u; float f; } x; x.u = u; return x.f;
}

__global__ __launch_bounds__(256) void gru_lag(
    const float* __restrict__ x,      // (S,B,1)
    const float* __restrict__ h_in,   // (2,B,H)
    const float* __restrict__ W_ih0,  // (96,1)
    const float* __restrict__ W_hh0,  // (96,32)
    const float* __restrict__ b_ih0,  // (96)
    const float* __restrict__ b_hh0,  // (96)
    const float* __restrict__ W_ih1,  // (96,32)
    const float* __restrict__ W_hh1,  // (96,32)
    const float* __restrict__ b_ih1,  // (96)
    const float* __restrict__ b_hh1,  // (96)
    const float* __restrict__ W_out,  // (1,32)
    const float* __restrict__ b_out,  // (1)
    float* __restrict__ out)          // y (S*B) then h_state (2,B,H)
{
    __shared__ __align__(16) unsigned short sh0[2][16 * RS];  // h0 bf16
    __shared__ __align__(16) unsigned short sh1[2][16 * RS];  // h1 bf16
    __shared__ __align__(16) float sx[S_LEN * 16];            // staged x
    __shared__ __align__(16) float sy[S_LEN * 16];            // buffered y

    const int tid  = threadIdx.x;
    const int w    = tid >> 6;        // 0,1 -> layer 0; 2,3 -> layer 1
    const int lane = tid & 63;
    const int n    = lane & 15;       // batch col / A-row index
    const int q    = lane >> 4;       // quad
    const int base = blockIdx.x * 16;
    const int bn   = base + n;
    const int wl   = w & 1;           // hidden half within the layer

    // ---- stage x (coalesced float4, all waves) ----
    for (int s = tid; s < S_LEN * 4; s += 256) {
        const int t = s >> 2, c = s & 3;
        *(float4*)&sx[t * 16 + c * 4] = *(const float4*)&x[t * B_SZ + base + c * 4];
    }

    const float SRZ = -1.4426950408889634f;  // -log2(e)   (sigmoid gates)
    const float SN  =  2.8853900817779268f;  //  2*log2(e) (tanh gate)

    // ---- per-role persistent weights ----
    short8 A_h[3], A_i[3];
    f32x4  C_h[3], C_i3;
    float  wi0r[4], wi0z[4], wi0n[4], bi0n[4];   // L0 input weights (w01)
    float  wo8[8];                                // head weights (wave 2)
    float  hd[4];                                 // own h half, fp32

    if (w < 2) {
#pragma unroll
        for (int t = 0; t < 3; ++t) {
            const float sc = (t < 2) ? SRZ : SN;
            const int row = 32 * t + 16 * wl + n;
#pragma unroll
            for (int e = 0; e < 8; ++e)
                A_h[t][e] = (short)bf_rne1(W_hh0[row * H_SZ + q * 8 + e] * sc);
#pragma unroll
            for (int r = 0; r < 4; ++r) {
                const int g = 32 * t + 16 * wl + 4 * q + r;
                C_h[t][r] = (t < 2) ? SRZ * (b_ih0[g] + b_hh0[g])
                                    : SN * b_hh0[g];
            }
        }
#pragma unroll
        for (int r = 0; r < 4; ++r) {
            const int j = 16 * wl + 4 * q + r;
            wi0r[r] = SRZ * W_ih0[j];
            wi0z[r] = SRZ * W_ih0[32 + j];
            wi0n[r] = SN  * W_ih0[64 + j];
            bi0n[r] = SN  * b_ih0[64 + j];
            hd[r]   = h_in[bn * H_SZ + j];
        }
    } else {
#pragma unroll
        for (int t = 0; t < 3; ++t) {
            const float sc = (t < 2) ? SRZ : SN;
            const int row = 32 * t + 16 * wl + n;
#pragma unroll
            for (int e = 0; e < 8; ++e) {
                A_h[t][e] = (short)bf_rne1(W_hh1[row * H_SZ + q * 8 + e] * sc);
                A_i[t][e] = (short)bf_rne1(W_ih1[row * H_SZ + q * 8 + e] * sc);
            }
#pragma unroll
            for (int r = 0; r < 4; ++r) {
                const int g = 32 * t + 16 * wl + 4 * q + r;
                C_h[t][r] = (t < 2) ? SRZ * (b_ih1[g] + b_hh1[g])
                                    : SN * b_hh1[g];
                if (t == 2) C_i3[r] = SN * b_ih1[g];
            }
        }
#pragma unroll
        for (int r = 0; r < 4; ++r)
            hd[r] = h_in[B_SZ * H_SZ + bn * H_SZ + 16 * wl + 4 * q + r];
#pragma unroll
        for (int e = 0; e < 8; ++e) wo8[e] = W_out[q * 8 + e];
    }
    const f32x4 Z4 = {0.f, 0.f, 0.f, 0.f};
    const float bout = b_out[0];

    // ---- initial B fragments (bf16 from h_in) ----
    short8 B0, B1;   // w01: B0 = h0(i-1). w23: B0 = h0(i-1), B1 = h1(i-2).
    {
        const float* hsrc = h_in + (size_t)(w >= 2) * B_SZ * H_SZ + bn * H_SZ + q * 8;
        union { short8 s8; unsigned u[4]; } f;
        const float4 a = *(const float4*)&hsrc[0];
        const float4 b = *(const float4*)&hsrc[4];
        f.u[0] = pk2(a.x, a.y); f.u[1] = pk2(a.z, a.w);
        f.u[2] = pk2(b.x, b.y); f.u[3] = pk2(b.z, b.w);
        if (w < 2) B0 = f.s8; else B1 = f.s8;
    }

    const int wroff = n * RS + 16 * wl + 4 * q;   // b64 write (shorts)
    const int rdoff = n * RS + 8 * q;             // b128 read (shorts)

    __syncthreads();   // x staged
    float xcur = (w < 2) ? sx[n] : 0.0f;

#pragma unroll 2
    for (int i = 0; i <= S_LEN; ++i) {
        const int buf = i & 1;
        // ---------------- pre-barrier compute ----------------
        if (w < 2) {
            if (i < S_LEN) {
                // h0(i) from B0 = h0(i-1): the true-dependency path.
                const f32x4 Dr = MFMA(A_h[0], B0, C_h[0]);
                const f32x4 Dz = MFMA(A_h[1], B0, C_h[1]);
                const f32x4 Dn = MFMA(A_h[2], B0, C_h[2]);
                float hv4[4];
#pragma unroll
                for (int r = 0; r < 4; ++r) {
                    const float rg = sigm_pre(fmaf(xcur, wi0r[r], Dr[r]));
                    const float zg = sigm_pre(fmaf(xcur, wi0z[r], Dz[r]));
                    const float ng = tanh_pre(fmaf(rg, Dn[r],
                                                   fmaf(xcur, wi0n[r], bi0n[r])));
                    const float v = fmaf(zg, hd[r] - ng, ng);
                    hd[r] = v;
                    hv4[r] = v;
                }
                *(uint2*)&sh0[buf][wroff] =
                    make_uint2(pk2(hv4[0], hv4[1]), pk2(hv4[2], hv4[3]));
            }
        } else {
            if (i > 0) {
                // h1(i-1) from B1 = h1(i-2), B0 = h0(i-1): both prefetched
                // at iter i-1 post-barrier -> no read stall here.
                const f32x4 Ur = MFMA(A_h[0], B1, C_h[0]);
                const f32x4 Uz = MFMA(A_h[1], B1, C_h[1]);
                const f32x4 Un = MFMA(A_h[2], B1, C_h[2]);
                const f32x4 Vr = MFMA(A_i[0], B0, Z4);
                const f32x4 Vz = MFMA(A_i[1], B0, Z4);
                const f32x4 Vn = MFMA(A_i[2], B0, C_i3);
                float hv4[4];
#pragma unroll
                for (int r = 0; r < 4; ++r) {
                    const float rg = sigm_pre(Ur[r] + Vr[r]);
                    const float zg = sigm_pre(Uz[r] + Vz[r]);
                    const float ng = tanh_pre(fmaf(rg, Un[r], Vn[r]));
                    const float v = fmaf(zg, hd[r] - ng, ng);
                    hd[r] = v;
                    hv4[r] = v;
                }
                *(uint2*)&sh1[buf][wroff] =
                    make_uint2(pk2(hv4[0], hv4[1]), pk2(hv4[2], hv4[3]));
            }
        }

        __syncthreads();   // lgkm-only drain (no global ops in loop)

        // ---------------- post-barrier reads (prefetch for next iter) ------
        if (w < 2) {
            if (i < S_LEN) {
                B0 = *(const short8*)&sh0[buf][rdoff];          // h0(i)
                const int tn = (i + 1 < S_LEN) ? i + 1 : i;
                xcur = sx[tn * 16 + n];                          // x(i+1)
            }
        } else {
            if (i < S_LEN)
                B0 = *(const short8*)&sh0[buf][rdoff];          // h0(i)
            if (i > 0) {
                B1 = *(const short8*)&sh1[buf][rdoff];          // h1(i-1)
                if (w == 2) {
                    // y(i-1) from the just-read bf16 h1 fragment
                    union { short8 s8; unsigned u[4]; } f; f.s8 = B1;
                    float ys = bits_f(f.u[0] << 16) * wo8[0];
                    ys = fmaf(bits_f(f.u[0] & 0xffff0000u), wo8[1], ys);
                    ys = fmaf(bits_f(f.u[1] << 16),         wo8[2], ys);
                    ys = fmaf(bits_f(f.u[1] & 0xffff0000u), wo8[3], ys);
                    ys = fmaf(bits_f(f.u[2] << 16),         wo8[4], ys);
                    ys = fmaf(bits_f(f.u[2] & 0xffff0000u), wo8[5], ys);
                    ys = fmaf(bits_f(f.u[3] << 16),         wo8[6], ys);
                    ys = fmaf(bits_f(f.u[3] & 0xffff0000u), wo8[7], ys);
                    ys += __shfl_xor(ys, 16);
                    ys += __shfl_xor(ys, 32);
                    if (lane < 16) sy[(i - 1) * 16 + n] = ys;
                }
            }
        }
    }

    __syncthreads();   // sy complete

    // ---- flush y (coalesced float4 + bias) ----
    for (int s = tid; s < S_LEN * 4; s += 256) {
        const int t = s >> 2, c = s & 3;
        const float4 a = *(const float4*)&sy[t * 16 + c * 4];
        *(float4*)&out[t * B_SZ + base + c * 4] =
            make_float4(a.x + bout, a.y + bout, a.z + bout, a.w + bout);
    }

    // ---- final h_state: out = y (S*B) ++ h0 (B*H) ++ h1 (B*H) ----
    const size_t hoff = (size_t)S_LEN * B_SZ + (size_t)(w >= 2) * B_SZ * H_SZ;
    *(float4*)&out[hoff + bn * H_SZ + 16 * wl + 4 * q] =
        make_float4(hd[0], hd[1], hd[2], hd[3]);
}

extern "C" void kernel_launch(void* const* d_in, const int* in_sizes, int n_in,
                              void* d_out, int out_size, void* d_ws, size_t ws_size,
                              hipStream_t stream) {
    (void)in_sizes; (void)n_in; (void)out_size; (void)d_ws; (void)ws_size;
    const float* x     = (const float*)d_in[0];
    const float* h_in  = (const float*)d_in[1];
    const float* W_ih0 = (const float*)d_in[2];
    const float* W_hh0 = (const float*)d_in[3];
    const float* b_ih0 = (const float*)d_in[4];
    const float* b_hh0 = (const float*)d_in[5];
    const float* W_ih1 = (const float*)d_in[6];
    const float* W_hh1 = (const float*)d_in[7];
    const float* b_ih1 = (const float*)d_in[8];
    const float* b_hh1 = (const float*)d_in[9];
    const float* W_out = (const float*)d_in[10];
    const float* b_out = (const float*)d_in[11];

    dim3 grid(B_SZ / 16);   // 512 blocks x 4 waves = 2048 waves (2/SIMD)
    dim3 block(256);
    gru_lag<<<grid, block, 0, stream>>>(x, h_in, W_ih0, W_hh0, b_ih0, b_hh0,
                                        W_ih1, W_hh1, b_ih1, b_hh1,
                                        W_out, b_out, (float*)d_out);
}

// Round 11
// 241.985 us; speedup vs baseline: 1.5422x; 1.1047x over previous
//
#include <hip/hip_runtime.h>

// Fused 2-layer GRU, round 11: R10 skeleton + issue-count cleanup.
// S=256, B=8192, IN=1, H=32, L=2.
//
// 512 blocks x 256 thr (4 waves); block owns 16 batch elements.
// Waves 0,1: layer 0 (hidden half wl) -- true-dependency path.
// Waves 2,3: layer 1, lagged one step (operands prefetched last iter).
// Changes vs R10 (all issue-count cuts, same exchange structure):
//  - y(i-1) computed by wave 2 with ONE MFMA on a one-row W_out A-fragment
//    (replaces ~26-instr bf16 unpack-dot + 2 shuffles).
//  - i=0 and i=S peeled; hot loop i=1..S-1 has no per-iter predication.
//  - x(i+1) prefetched PRE-barrier (sx is read-only).
//  - direct __builtin_amdgcn_exp2f / rcpf (no guarded fallback path).
// h exchanged in bf16 B-fragment layout (direct ds_read_b128, zero repack).
// No global ops inside the loop.

#define S_LEN 256
#define B_SZ  8192
#define H_SZ  32
#define RS    40     // LDS row stride in shorts (80 B)

typedef __attribute__((ext_vector_type(8))) short short8;  // 8 bf16
typedef __attribute__((ext_vector_type(4))) float f32x4;   // MFMA C/D

#define MFMA(a, b, c) __builtin_amdgcn_mfma_f32_16x16x32_bf16(a, b, c, 0, 0, 0)

__device__ __forceinline__ float sigm_pre(float p) {   // p = -log2e * v
    return __builtin_amdgcn_rcpf(1.0f + __builtin_amdgcn_exp2f(p));
}
__device__ __forceinline__ float tanh_pre(float p) {   // p = 2*log2e * v
    return 1.0f - 2.0f * __builtin_amdgcn_rcpf(1.0f + __builtin_amdgcn_exp2f(p));
}

__device__ __forceinline__ unsigned short bf_rne1(float f) {
    union { float f; unsigned u; } x; x.f = f;
    unsigned u = x.u + 0x7fffu + ((x.u >> 16) & 1u);
    return (unsigned short)(u >> 16);
}

#if __has_builtin(__builtin_amdgcn_cvt_pk_bf16_f32)
typedef __bf16 bf16x2 __attribute__((ext_vector_type(2)));
__device__ __forceinline__ unsigned pk2(float a, float b) {
    union { bf16x2 v; unsigned u; } c;
    c.v = __builtin_amdgcn_cvt_pk_bf16_f32(a, b);
    return c.u;
}
#else
__device__ __forceinline__ unsigned pk2(float a, float b) {
    return (unsigned)bf_rne1(a) | ((unsigned)bf_rne1(b) << 16);
}
#endif

__global__ __launch_bounds__(256) void gru_cln(
    const float* __restrict__ x,      // (S,B,1)
    const float* __restrict__ h_in,   // (2,B,H)
    const float* __restrict__ W_ih0,  // (96,1)
    const float* __restrict__ W_hh0,  // (96,32)
    const float* __restrict__ b_ih0,  // (96)
    const float* __restrict__ b_hh0,  // (96)
    const float* __restrict__ W_ih1,  // (96,32)
    const float* __restrict__ W_hh1,  // (96,32)
    const float* __restrict__ b_ih1,  // (96)
    const float* __restrict__ b_hh1,  // (96)
    const float* __restrict__ W_out,  // (1,32)
    const float* __restrict__ b_out,  // (1)
    float* __restrict__ out)          // y (S*B) then h_state (2,B,H)
{
    __shared__ __align__(16) unsigned short sh0[2][16 * RS];  // h0 bf16
    __shared__ __align__(16) unsigned short sh1[2][16 * RS];  // h1 bf16
    __shared__ __align__(16) float sx[(S_LEN + 1) * 16];      // staged x (+pad)
    __shared__ __align__(16) float sy[S_LEN * 16];            // buffered y

    const int tid  = threadIdx.x;
    const int w    = tid >> 6;        // 0,1 -> layer 0; 2,3 -> layer 1
    const int lane = tid & 63;
    const int n    = lane & 15;       // batch col / A-row index
    const int q    = lane >> 4;       // quad
    const int base = blockIdx.x * 16;
    const int bn   = base + n;
    const int wl   = w & 1;           // hidden half within the layer

    // ---- stage x (coalesced float4, all waves) ----
    for (int s = tid; s < S_LEN * 4; s += 256) {
        const int t = s >> 2, c = s & 3;
        *(float4*)&sx[t * 16 + c * 4] = *(const float4*)&x[t * B_SZ + base + c * 4];
    }

    const float SRZ = -1.4426950408889634f;  // -log2(e)   (sigmoid gates)
    const float SN  =  2.8853900817779268f;  //  2*log2(e) (tanh gate)

    // ---- per-role persistent weights ----
    short8 A_h[3], A_i[3];
    f32x4  C_h[3], C_i3;
    float  wi0r[4], wi0z[4], wi0n[4], bi0n[4];   // L0 input weights (w01)
    short8 Awo = {0, 0, 0, 0, 0, 0, 0, 0};       // y head A-frag (wave 2)
    float  hd[4];                                 // own h half, fp32

    if (w < 2) {
#pragma unroll
        for (int t = 0; t < 3; ++t) {
            const float sc = (t < 2) ? SRZ : SN;
            const int row = 32 * t + 16 * wl + n;
#pragma unroll
            for (int e = 0; e < 8; ++e)
                A_h[t][e] = (short)bf_rne1(W_hh0[row * H_SZ + q * 8 + e] * sc);
#pragma unroll
            for (int r = 0; r < 4; ++r) {
                const int g = 32 * t + 16 * wl + 4 * q + r;
                C_h[t][r] = (t < 2) ? SRZ * (b_ih0[g] + b_hh0[g])
                                    : SN * b_hh0[g];
            }
        }
#pragma unroll
        for (int r = 0; r < 4; ++r) {
            const int j = 16 * wl + 4 * q + r;
            wi0r[r] = SRZ * W_ih0[j];
            wi0z[r] = SRZ * W_ih0[32 + j];
            wi0n[r] = SN  * W_ih0[64 + j];
            bi0n[r] = SN  * b_ih0[64 + j];
            hd[r]   = h_in[bn * H_SZ + j];
        }
    } else {
#pragma unroll
        for (int t = 0; t < 3; ++t) {
            const float sc = (t < 2) ? SRZ : SN;
            const int row = 32 * t + 16 * wl + n;
#pragma unroll
            for (int e = 0; e < 8; ++e) {
                A_h[t][e] = (short)bf_rne1(W_hh1[row * H_SZ + q * 8 + e] * sc);
                A_i[t][e] = (short)bf_rne1(W_ih1[row * H_SZ + q * 8 + e] * sc);
            }
#pragma unroll
            for (int r = 0; r < 4; ++r) {
                const int g = 32 * t + 16 * wl + 4 * q + r;
                C_h[t][r] = (t < 2) ? SRZ * (b_ih1[g] + b_hh1[g])
                                    : SN * b_hh1[g];
                if (t == 2) C_i3[r] = SN * b_ih1[g];
            }
        }
#pragma unroll
        for (int r = 0; r < 4; ++r)
            hd[r] = h_in[B_SZ * H_SZ + bn * H_SZ + 16 * wl + 4 * q + r];
        if (w == 2) {
            // one-row head fragment: row 0 (lanes with n==0) = W_out
#pragma unroll
            for (int e = 0; e < 8; ++e)
                Awo[e] = (n == 0) ? (short)bf_rne1(W_out[q * 8 + e]) : (short)0;
        }
    }
    const f32x4 Z4 = {0.f, 0.f, 0.f, 0.f};
    const float bout = b_out[0];

    // ---- initial B fragments (bf16 from h_in) ----
    short8 B0, B1;   // w01: B0 = h0(i-1). w23: B0 = h0(i-1), B1 = h1(i-2).
    {
        const float* hsrc = h_in + (size_t)(w >= 2) * B_SZ * H_SZ + bn * H_SZ + q * 8;
        union { short8 s8; unsigned u[4]; } f;
        const float4 a = *(const float4*)&hsrc[0];
        const float4 b = *(const float4*)&hsrc[4];
        f.u[0] = pk2(a.x, a.y); f.u[1] = pk2(a.z, a.w);
        f.u[2] = pk2(b.x, b.y); f.u[3] = pk2(b.z, b.w);
        if (w < 2) B0 = f.s8; else B1 = f.s8;
    }

    const int wroff = n * RS + 16 * wl + 4 * q;   // b64 write (shorts)
    const int rdoff = n * RS + 8 * q;             // b128 read (shorts)

    __syncthreads();   // x staged
    float xcur = sx[n];

    // ================= iter 0 (peeled): w01 compute h0(0) =================
    if (w < 2) {
        const f32x4 Dr = MFMA(A_h[0], B0, C_h[0]);
        const f32x4 Dz = MFMA(A_h[1], B0, C_h[1]);
        const f32x4 Dn = MFMA(A_h[2], B0, C_h[2]);
        float hv4[4];
#pragma unroll
        for (int r = 0; r < 4; ++r) {
            const float rg = sigm_pre(fmaf(xcur, wi0r[r], Dr[r]));
            const float zg = sigm_pre(fmaf(xcur, wi0z[r], Dz[r]));
            const float ng = tanh_pre(fmaf(rg, Dn[r],
                                           fmaf(xcur, wi0n[r], bi0n[r])));
            const float v = fmaf(zg, hd[r] - ng, ng);
            hd[r] = v;
            hv4[r] = v;
        }
        *(uint2*)&sh0[0][wroff] =
            make_uint2(pk2(hv4[0], hv4[1]), pk2(hv4[2], hv4[3]));
        xcur = sx[16 + n];   // x(1)
    }
    __syncthreads();
    B0 = *(const short8*)&sh0[0][rdoff];   // h0(0) for all waves

    // ================= hot loop i = 1 .. S-1 (no predication) ==============
#pragma unroll 2
    for (int i = 1; i < S_LEN; ++i) {
        const int buf = i & 1;
        if (w < 2) {
            // h0(i) from B0 = h0(i-1): the true-dependency path.
            const f32x4 Dr = MFMA(A_h[0], B0, C_h[0]);
            const f32x4 Dz = MFMA(A_h[1], B0, C_h[1]);
            const f32x4 Dn = MFMA(A_h[2], B0, C_h[2]);
            float hv4[4];
#pragma unroll
            for (int r = 0; r < 4; ++r) {
                const float rg = sigm_pre(fmaf(xcur, wi0r[r], Dr[r]));
                const float zg = sigm_pre(fmaf(xcur, wi0z[r], Dz[r]));
                const float ng = tanh_pre(fmaf(rg, Dn[r],
                                               fmaf(xcur, wi0n[r], bi0n[r])));
                const float v = fmaf(zg, hd[r] - ng, ng);
                hd[r] = v;
                hv4[r] = v;
            }
            *(uint2*)&sh0[buf][wroff] =
                make_uint2(pk2(hv4[0], hv4[1]), pk2(hv4[2], hv4[3]));
            xcur = sx[(i + 1) * 16 + n];   // read-only prefetch, pre-barrier
        } else {
            // h1(i-1) from B1 = h1(i-2), B0 = h0(i-1): prefetched last iter.
            const f32x4 Ur = MFMA(A_h[0], B1, C_h[0]);
            const f32x4 Uz = MFMA(A_h[1], B1, C_h[1]);
            const f32x4 Un = MFMA(A_h[2], B1, C_h[2]);
            const f32x4 Vr = MFMA(A_i[0], B0, Z4);
            const f32x4 Vz = MFMA(A_i[1], B0, Z4);
            const f32x4 Vn = MFMA(A_i[2], B0, C_i3);
            float hv4[4];
#pragma unroll
            for (int r = 0; r < 4; ++r) {
                const float rg = sigm_pre(Ur[r] + Vr[r]);
                const float zg = sigm_pre(Uz[r] + Vz[r]);
                const float ng = tanh_pre(fmaf(rg, Un[r], Vn[r]));
                const float v = fmaf(zg, hd[r] - ng, ng);
                hd[r] = v;
                hv4[r] = v;
            }
            *(uint2*)&sh1[buf][wroff] =
                make_uint2(pk2(hv4[0], hv4[1]), pk2(hv4[2], hv4[3]));
        }

        __syncthreads();   // lgkm-only drain

        if (w < 2) {
            B0 = *(const short8*)&sh0[buf][rdoff];          // h0(i)
        } else {
            B0 = *(const short8*)&sh0[buf][rdoff];          // h0(i)
            B1 = *(const short8*)&sh1[buf][rdoff];          // h1(i-1)
            if (w == 2) {
                // y(i-1) = W_out . h1(i-1): one MFMA, row 0 = result.
                const f32x4 yD = MFMA(Awo, B1, Z4);
                if (lane < 16) sy[(i - 1) * 16 + n] = yD[0];
            }
        }
    }

    // ================= iter S (peeled): w23 compute h1(S-1) ================
    if (w >= 2) {
        const f32x4 Ur = MFMA(A_h[0], B1, C_h[0]);
        const f32x4 Uz = MFMA(A_h[1], B1, C_h[1]);
        const f32x4 Un = MFMA(A_h[2], B1, C_h[2]);
        const f32x4 Vr = MFMA(A_i[0], B0, Z4);
        const f32x4 Vz = MFMA(A_i[1], B0, Z4);
        const f32x4 Vn = MFMA(A_i[2], B0, C_i3);
        float hv4[4];
#pragma unroll
        for (int r = 0; r < 4; ++r) {
            const float rg = sigm_pre(Ur[r] + Vr[r]);
            const float zg = sigm_pre(Uz[r] + Vz[r]);
            const float ng = tanh_pre(fmaf(rg, Un[r], Vn[r]));
            const float v = fmaf(zg, hd[r] - ng, ng);
            hd[r] = v;
            hv4[r] = v;
        }
        *(uint2*)&sh1[0][wroff] =
            make_uint2(pk2(hv4[0], hv4[1]), pk2(hv4[2], hv4[3]));
    }
    __syncthreads();
    if (w == 2) {
        B1 = *(const short8*)&sh1[0][rdoff];               // h1(S-1)
        const f32x4 yD = MFMA(Awo, B1, Z4);
        if (lane < 16) sy[(S_LEN - 1) * 16 + n] = yD[0];
    }
    __syncthreads();   // sy complete

    // ---- flush y (coalesced float4 + bias) ----
    for (int s = tid; s < S_LEN * 4; s += 256) {
        const int t = s >> 2, c = s & 3;
        const float4 a = *(const float4*)&sy[t * 16 + c * 4];
        *(float4*)&out[t * B_SZ + base + c * 4] =
            make_float4(a.x + bout, a.y + bout, a.z + bout, a.w + bout);
    }

    // ---- final h_state: out = y (S*B) ++ h0 (B*H) ++ h1 (B*H) ----
    const size_t hoff = (size_t)S_LEN * B_SZ + (size_t)(w >= 2) * B_SZ * H_SZ;
    *(float4*)&out[hoff + bn * H_SZ + 16 * wl + 4 * q] =
        make_float4(hd[0], hd[1], hd[2], hd[3]);
}

extern "C" void kernel_launch(void* const* d_in, const int* in_sizes, int n_in,
                              void* d_out, int out_size, void* d_ws, size_t ws_size,
                              hipStream_t stream) {
    (void)in_sizes; (void)n_in; (void)out_size; (void)d_ws; (void)ws_size;
    const float* x     = (const float*)d_in[0];
    const float* h_in  = (const float*)d_in[1];
    const float* W_ih0 = (const float*)d_in[2];
    const float* W_hh0 = (const float*)d_in[3];
    const float* b_ih0 = (const float*)d_in[4];
    const float* b_hh0 = (const float*)d_in[5];
    const float* W_ih1 = (const float*)d_in[6];
    const float* W_hh1 = (const float*)d_in[7];
    const float* b_ih1 = (const float*)d_in[8];
    const float* b_hh1 = (const float*)d_in[9];
    const float* W_out = (const float*)d_in[10];
    const float* b_out = (const float*)d_in[11];

    dim3 grid(B_SZ / 16);   // 512 blocks x 4 waves = 2048 waves (2/SIMD)
    dim3 block(256);
    gru_cln<<<grid, block, 0, stream>>>(x, h_in, W_ih0, W_hh0, b_ih0, b_hh0,
                                        W_ih1, W_hh1, b_ih1, b_hh1,
                                        W_out, b_out, (float*)d_out);
}

// Round 12
// 231.951 us; speedup vs baseline: 1.6089x; 1.0433x over previous
//
#include <hip/hip_runtime.h>

// Fused 2-layer GRU, round 12: R11 + x-gates via MFMA + V-chained MFMAs.
// S=256, B=8192, IN=1, H=32, L=2.
//
// 512 blocks x 256 thr (4 waves); block owns 16 batch elements.
// Waves 0,1: layer 0 (hidden half wl) -- true-dependency path, s_setprio(1).
//   x contribution computed on the MFMA pipe: one-column A_x fragments
//   (k=0 only) x a Bx fragment carrying bf16(x) in k=0 -- removes 12
//   VALU fmas/iter. Bx is fully zero-initialized once (avoids 0*garbage).
// Waves 2,3: layer 1, lagged one step; ih-side MFMAs CHAINED onto hh-side
//   accumulators (removes 8 combine-adds/iter); n-gate keeps 2 accumulators.
// y via one-row W_out MFMA on wave 2 (R11). h exchanged in bf16 B-fragment
// layout (direct ds_read_b128). No global ops inside the loop.

#define S_LEN 256
#define B_SZ  8192
#define H_SZ  32
#define RS    40     // LDS row stride in shorts (80 B)

typedef __attribute__((ext_vector_type(8))) short short8;  // 8 bf16
typedef __attribute__((ext_vector_type(4))) float f32x4;   // MFMA C/D

#define MFMA(a, b, c) __builtin_amdgcn_mfma_f32_16x16x32_bf16(a, b, c, 0, 0, 0)

__device__ __forceinline__ float sigm_pre(float p) {   // p = -log2e * v
    return __builtin_amdgcn_rcpf(1.0f + __builtin_amdgcn_exp2f(p));
}
__device__ __forceinline__ float tanh_pre(float p) {   // p = 2*log2e * v
    return 1.0f - 2.0f * __builtin_amdgcn_rcpf(1.0f + __builtin_amdgcn_exp2f(p));
}

__device__ __forceinline__ unsigned short bf_rne1(float f) {
    union { float f; unsigned u; } x; x.f = f;
    unsigned u = x.u + 0x7fffu + ((x.u >> 16) & 1u);
    return (unsigned short)(u >> 16);
}

#if __has_builtin(__builtin_amdgcn_cvt_pk_bf16_f32)
typedef __bf16 bf16x2 __attribute__((ext_vector_type(2)));
__device__ __forceinline__ unsigned pk2(float a, float b) {
    union { bf16x2 v; unsigned u; } c;
    c.v = __builtin_amdgcn_cvt_pk_bf16_f32(a, b);
    return c.u;
}
#else
__device__ __forceinline__ unsigned pk2(float a, float b) {
    return (unsigned)bf_rne1(a) | ((unsigned)bf_rne1(b) << 16);
}
#endif

union Frag8 { short8 s8; unsigned u[4]; };

__global__ __launch_bounds__(256) void gru_xm(
    const float* __restrict__ x,      // (S,B,1)
    const float* __restrict__ h_in,   // (2,B,H)
    const float* __restrict__ W_ih0,  // (96,1)
    const float* __restrict__ W_hh0,  // (96,32)
    const float* __restrict__ b_ih0,  // (96)
    const float* __restrict__ b_hh0,  // (96)
    const float* __restrict__ W_ih1,  // (96,32)
    const float* __restrict__ W_hh1,  // (96,32)
    const float* __restrict__ b_ih1,  // (96)
    const float* __restrict__ b_hh1,  // (96)
    const float* __restrict__ W_out,  // (1,32)
    const float* __restrict__ b_out,  // (1)
    float* __restrict__ out)          // y (S*B) then h_state (2,B,H)
{
    __shared__ __align__(16) unsigned short sh0[2][16 * RS];  // h0 bf16
    __shared__ __align__(16) unsigned short sh1[2][16 * RS];  // h1 bf16
    __shared__ __align__(16) float sx[(S_LEN + 1) * 16];      // staged x (+pad)
    __shared__ __align__(16) float sy[S_LEN * 16];            // buffered y

    const int tid  = threadIdx.x;
    const int w    = tid >> 6;        // 0,1 -> layer 0; 2,3 -> layer 1
    const int lane = tid & 63;
    const int n    = lane & 15;       // batch col / A-row index
    const int q    = lane >> 4;       // quad
    const int base = blockIdx.x * 16;
    const int bn   = base + n;
    const int wl   = w & 1;           // hidden half within the layer

    // ---- stage x (coalesced float4, all waves) ----
    for (int s = tid; s < S_LEN * 4; s += 256) {
        const int t = s >> 2, c = s & 3;
        *(float4*)&sx[t * 16 + c * 4] = *(const float4*)&x[t * B_SZ + base + c * 4];
    }

    const float SRZ = -1.4426950408889634f;  // -log2(e)   (sigmoid gates)
    const float SN  =  2.8853900817779268f;  //  2*log2(e) (tanh gate)

    // ---- per-role persistent weights ----
    short8 A_h[3], A_i[3];                        // recurrent / (L1 ih | L0 x)
    f32x4  C_h[3], C_i3;
    short8 Awo = {0, 0, 0, 0, 0, 0, 0, 0};        // y head A-frag (wave 2)
    short8 Bx  = {0, 0, 0, 0, 0, 0, 0, 0};        // x B-frag (w01), k=0 slot
    float  hd[4];                                  // own h half, fp32

    if (w < 2) {
#pragma unroll
        for (int t = 0; t < 3; ++t) {
            const float sc = (t < 2) ? SRZ : SN;
            const int row = 32 * t + 16 * wl + n;
#pragma unroll
            for (int e = 0; e < 8; ++e)
                A_h[t][e] = (short)bf_rne1(W_hh0[row * H_SZ + q * 8 + e] * sc);
            // one-column x-weight fragment: k=0 only (q==0 && e==0)
#pragma unroll
            for (int e = 0; e < 8; ++e)
                A_i[t][e] = (q == 0 && e == 0)
                            ? (short)bf_rne1(W_ih0[row] * sc) : (short)0;
#pragma unroll
            for (int r = 0; r < 4; ++r) {
                const int g = 32 * t + 16 * wl + 4 * q + r;
                C_h[t][r] = (t < 2) ? SRZ * (b_ih0[g] + b_hh0[g])
                                    : SN * b_hh0[g];
                if (t == 2) C_i3[r] = SN * b_ih0[g];   // n-gate ih bias
            }
        }
#pragma unroll
        for (int r = 0; r < 4; ++r)
            hd[r] = h_in[bn * H_SZ + 16 * wl + 4 * q + r];
    } else {
#pragma unroll
        for (int t = 0; t < 3; ++t) {
            const float sc = (t < 2) ? SRZ : SN;
            const int row = 32 * t + 16 * wl + n;
#pragma unroll
            for (int e = 0; e < 8; ++e) {
                A_h[t][e] = (short)bf_rne1(W_hh1[row * H_SZ + q * 8 + e] * sc);
                A_i[t][e] = (short)bf_rne1(W_ih1[row * H_SZ + q * 8 + e] * sc);
            }
#pragma unroll
            for (int r = 0; r < 4; ++r) {
                const int g = 32 * t + 16 * wl + 4 * q + r;
                C_h[t][r] = (t < 2) ? SRZ * (b_ih1[g] + b_hh1[g])
                                    : SN * b_hh1[g];
                if (t == 2) C_i3[r] = SN * b_ih1[g];
            }
        }
#pragma unroll
        for (int r = 0; r < 4; ++r)
            hd[r] = h_in[B_SZ * H_SZ + bn * H_SZ + 16 * wl + 4 * q + r];
        if (w == 2) {
#pragma unroll
            for (int e = 0; e < 8; ++e)
                Awo[e] = (n == 0) ? (short)bf_rne1(W_out[q * 8 + e]) : (short)0;
        }
    }
    const f32x4 Z4 = {0.f, 0.f, 0.f, 0.f};
    const float bout = b_out[0];

    // ---- initial B fragments (bf16 from h_in) ----
    short8 B0, B1;   // w01: B0 = h0(i-1). w23: B0 = h0(i-1), B1 = h1(i-2).
    {
        const float* hsrc = h_in + (size_t)(w >= 2) * B_SZ * H_SZ + bn * H_SZ + q * 8;
        Frag8 f;
        const float4 a = *(const float4*)&hsrc[0];
        const float4 b = *(const float4*)&hsrc[4];
        f.u[0] = pk2(a.x, a.y); f.u[1] = pk2(a.z, a.w);
        f.u[2] = pk2(b.x, b.y); f.u[3] = pk2(b.z, b.w);
        if (w < 2) B0 = f.s8; else B1 = f.s8;
    }

    const int wroff = n * RS + 16 * wl + 4 * q;   // b64 write (shorts)
    const int rdoff = n * RS + 8 * q;             // b128 read (shorts)

    __syncthreads();   // x staged
    float xcur = sx[n];
    if (w < 2) __builtin_amdgcn_s_setprio(1);   // true-dep path issues first

    // ================= iter 0 (peeled): w01 compute h0(0) =================
    if (w < 2) {
        Frag8 bxu; bxu.s8 = Bx; bxu.u[0] = pk2(xcur, xcur); Bx = bxu.s8;
        f32x4 Dr = MFMA(A_h[0], B0, C_h[0]);  Dr = MFMA(A_i[0], Bx, Dr);
        f32x4 Dz = MFMA(A_h[1], B0, C_h[1]);  Dz = MFMA(A_i[1], Bx, Dz);
        f32x4 Dn = MFMA(A_h[2], B0, C_h[2]);
        f32x4 Dxn = MFMA(A_i[2], Bx, C_i3);
        float hv4[4];
#pragma unroll
        for (int r = 0; r < 4; ++r) {
            const float rg = sigm_pre(Dr[r]);
            const float zg = sigm_pre(Dz[r]);
            const float ng = tanh_pre(fmaf(rg, Dn[r], Dxn[r]));
            const float v = fmaf(zg, hd[r] - ng, ng);
            hd[r] = v;
            hv4[r] = v;
        }
        *(uint2*)&sh0[0][wroff] =
            make_uint2(pk2(hv4[0], hv4[1]), pk2(hv4[2], hv4[3]));
        xcur = sx[16 + n];   // x(1)
    }
    __syncthreads();
    B0 = *(const short8*)&sh0[0][rdoff];   // h0(0) for all waves

    // ================= hot loop i = 1 .. S-1 (no predication) ==============
#pragma unroll 2
    for (int i = 1; i < S_LEN; ++i) {
        const int buf = i & 1;
        if (w < 2) {
            // h0(i) from B0 = h0(i-1): the true-dependency path.
            Frag8 bxu; bxu.s8 = Bx; bxu.u[0] = pk2(xcur, xcur); Bx = bxu.s8;
            f32x4 Dr = MFMA(A_h[0], B0, C_h[0]);  Dr = MFMA(A_i[0], Bx, Dr);
            f32x4 Dz = MFMA(A_h[1], B0, C_h[1]);  Dz = MFMA(A_i[1], Bx, Dz);
            f32x4 Dn = MFMA(A_h[2], B0, C_h[2]);
            f32x4 Dxn = MFMA(A_i[2], Bx, C_i3);
            float hv4[4];
#pragma unroll
            for (int r = 0; r < 4; ++r) {
                const float rg = sigm_pre(Dr[r]);
                const float zg = sigm_pre(Dz[r]);
                const float ng = tanh_pre(fmaf(rg, Dn[r], Dxn[r]));
                const float v = fmaf(zg, hd[r] - ng, ng);
                hd[r] = v;
                hv4[r] = v;
            }
            *(uint2*)&sh0[buf][wroff] =
                make_uint2(pk2(hv4[0], hv4[1]), pk2(hv4[2], hv4[3]));
            xcur = sx[(i + 1) * 16 + n];   // read-only prefetch, pre-barrier
        } else {
            // h1(i-1) from B1 = h1(i-2), B0 = h0(i-1): prefetched last iter.
            // ih-side chained onto hh-side accumulators (no combine-adds).
            f32x4 Gr = MFMA(A_h[0], B1, C_h[0]);  Gr = MFMA(A_i[0], B0, Gr);
            f32x4 Gz = MFMA(A_h[1], B1, C_h[1]);  Gz = MFMA(A_i[1], B0, Gz);
            f32x4 Un = MFMA(A_h[2], B1, C_h[2]);
            f32x4 Vn = MFMA(A_i[2], B0, C_i3);
            float hv4[4];
#pragma unroll
            for (int r = 0; r < 4; ++r) {
                const float rg = sigm_pre(Gr[r]);
                const float zg = sigm_pre(Gz[r]);
                const float ng = tanh_pre(fmaf(rg, Un[r], Vn[r]));
                const float v = fmaf(zg, hd[r] - ng, ng);
                hd[r] = v;
                hv4[r] = v;
            }
            *(uint2*)&sh1[buf][wroff] =
                make_uint2(pk2(hv4[0], hv4[1]), pk2(hv4[2], hv4[3]));
        }

        __syncthreads();   // lgkm-only drain

        if (w < 2) {
            B0 = *(const short8*)&sh0[buf][rdoff];          // h0(i)
        } else {
            B0 = *(const short8*)&sh0[buf][rdoff];          // h0(i)
            B1 = *(const short8*)&sh1[buf][rdoff];          // h1(i-1)
            if (w == 2) {
                // y(i-1) = W_out . h1(i-1): one MFMA, row 0 = result.
                const f32x4 yD = MFMA(Awo, B1, Z4);
                if (lane < 16) sy[(i - 1) * 16 + n] = yD[0];
            }
        }
    }

    // ================= iter S (peeled): w23 compute h1(S-1) ================
    if (w >= 2) {
        f32x4 Gr = MFMA(A_h[0], B1, C_h[0]);  Gr = MFMA(A_i[0], B0, Gr);
        f32x4 Gz = MFMA(A_h[1], B1, C_h[1]);  Gz = MFMA(A_i[1], B0, Gz);
        f32x4 Un = MFMA(A_h[2], B1, C_h[2]);
        f32x4 Vn = MFMA(A_i[2], B0, C_i3);
        float hv4[4];
#pragma unroll
        for (int r = 0; r < 4; ++r) {
            const float rg = sigm_pre(Gr[r]);
            const float zg = sigm_pre(Gz[r]);
            const float ng = tanh_pre(fmaf(rg, Un[r], Vn[r]));
            const float v = fmaf(zg, hd[r] - ng, ng);
            hd[r] = v;
            hv4[r] = v;
        }
        *(uint2*)&sh1[0][wroff] =
            make_uint2(pk2(hv4[0], hv4[1]), pk2(hv4[2], hv4[3]));
    }
    __syncthreads();
    if (w == 2) {
        B1 = *(const short8*)&sh1[0][rdoff];               // h1(S-1)
        const f32x4 yD = MFMA(Awo, B1, Z4);
        if (lane < 16) sy[(S_LEN - 1) * 16 + n] = yD[0];
    }
    __syncthreads();   // sy complete

    // ---- flush y (coalesced float4 + bias) ----
    for (int s = tid; s < S_LEN * 4; s += 256) {
        const int t = s >> 2, c = s & 3;
        const float4 a = *(const float4*)&sy[t * 16 + c * 4];
        *(float4*)&out[t * B_SZ + base + c * 4] =
            make_float4(a.x + bout, a.y + bout, a.z + bout, a.w + bout);
    }

    // ---- final h_state: out = y (S*B) ++ h0 (B*H) ++ h1 (B*H) ----
    const size_t hoff = (size_t)S_LEN * B_SZ + (size_t)(w >= 2) * B_SZ * H_SZ;
    *(float4*)&out[hoff + bn * H_SZ + 16 * wl + 4 * q] =
        make_float4(hd[0], hd[1], hd[2], hd[3]);
}

extern "C" void kernel_launch(void* const* d_in, const int* in_sizes, int n_in,
                              void* d_out, int out_size, void* d_ws, size_t ws_size,
                              hipStream_t stream) {
    (void)in_sizes; (void)n_in; (void)out_size; (void)d_ws; (void)ws_size;
    const float* x     = (const float*)d_in[0];
    const float* h_in  = (const float*)d_in[1];
    const float* W_ih0 = (const float*)d_in[2];
    const float* W_hh0 = (const float*)d_in[3];
    const float* b_ih0 = (const float*)d_in[4];
    const float* b_hh0 = (const float*)d_in[5];
    const float* W_ih1 = (const float*)d_in[6];
    const float* W_hh1 = (const float*)d_in[7];
    const float* b_ih1 = (const float*)d_in[8];
    const float* b_hh1 = (const float*)d_in[9];
    const float* W_out = (const float*)d_in[10];
    const float* b_out = (const float*)d_in[11];

    dim3 grid(B_SZ / 16);   // 512 blocks x 4 waves = 2048 waves (2/SIMD)
    dim3 block(256);
    gru_xm<<<grid, block, 0, stream>>>(x, h_in, W_ih0, W_hh0, b_ih0, b_hh0,
                                       W_ih1, W_hh1, b_ih1, b_hh1,
                                       W_out, b_out, (float*)d_out);
}